// Round 1
// baseline (807.368 us; speedup 1.0000x reference)
//
#include <hip/hip_runtime.h>
#include <hip/hip_bf16.h>
#include <cstddef>

// Problem constants
#define BB 8
#define DIM 256
#define HH 48
#define WW 48
#define HW 2304        // 48*48
#define HEADS 8
#define DH 32
#define BH 64          // B*HEADS
#define HK 24
#define WK 24
#define NN 576         // HK*WK
#define SCALE 0.17677669529663687f
#define EPSF 1e-5f

// ---------------------------------------------------------------------------
// Generic per-batch 1x1-conv GEMM: Y[b](o,m) = sum_c W[o,c] * X[b](c,m) + bias[o]
// O = 256, C = 256 fixed. TRANS=false: Y[b,o,m];  TRANS=true: Y[b,m,o].
// Tile: 64(o) x 64(m), K-chunk 16, 256 threads, 4x4 micro-tile per thread.
// ---------------------------------------------------------------------------
#define TO 64
#define TM 64
#define TKc 16

template <bool TRANS>
__global__ __launch_bounds__(256) void gemm_bias(const float* __restrict__ Wt,
                                                 const float* __restrict__ bias,
                                                 const float* __restrict__ X,
                                                 float* __restrict__ Y, int M) {
  __shared__ float As[TKc][TO + 4];
  __shared__ float Bs[TKc][TM + 4];
  const int b = blockIdx.z;
  const int oBase = blockIdx.y * TO;
  const int mBase = blockIdx.x * TM;
  const int tid = threadIdx.x;
  const int tx = tid & 15;   // -> m
  const int ty = tid >> 4;   // -> o
  const float* Xb = X + (size_t)b * 256 * (size_t)M;
  float acc[4][4] = {};

  for (int k0 = 0; k0 < 256; k0 += TKc) {
    // W tile 64(o) x 16(c); row-major W[o][c]
#pragma unroll
    for (int i = 0; i < 4; i++) {
      int idx = tid + i * 256;
      int o = idx >> 4, cc = idx & 15;
      As[cc][o] = Wt[(size_t)(oBase + o) * 256 + k0 + cc];
    }
    // X tile 16(c) x 64(m)
#pragma unroll
    for (int i = 0; i < 4; i++) {
      int idx = tid + i * 256;
      int cc = idx >> 6, mm = idx & 63;
      Bs[cc][mm] = Xb[(size_t)(k0 + cc) * M + mBase + mm];
    }
    __syncthreads();
#pragma unroll
    for (int kc = 0; kc < TKc; kc++) {
      float a0 = As[kc][ty * 4 + 0];
      float a1 = As[kc][ty * 4 + 1];
      float a2 = As[kc][ty * 4 + 2];
      float a3 = As[kc][ty * 4 + 3];
      float b0 = Bs[kc][tx * 4 + 0];
      float b1 = Bs[kc][tx * 4 + 1];
      float b2 = Bs[kc][tx * 4 + 2];
      float b3 = Bs[kc][tx * 4 + 3];
      acc[0][0] += a0 * b0; acc[0][1] += a0 * b1; acc[0][2] += a0 * b2; acc[0][3] += a0 * b3;
      acc[1][0] += a1 * b0; acc[1][1] += a1 * b1; acc[1][2] += a1 * b2; acc[1][3] += a1 * b3;
      acc[2][0] += a2 * b0; acc[2][1] += a2 * b1; acc[2][2] += a2 * b2; acc[2][3] += a2 * b3;
      acc[3][0] += a3 * b0; acc[3][1] += a3 * b1; acc[3][2] += a3 * b2; acc[3][3] += a3 * b3;
    }
    __syncthreads();
  }

#pragma unroll
  for (int i = 0; i < 4; i++) {
    int o = oBase + ty * 4 + i;
    float bs = bias[o];
#pragma unroll
    for (int j = 0; j < 4; j++) {
      int m = mBase + tx * 4 + j;
      if (!TRANS)
        Y[((size_t)b * 256 + o) * M + m] = acc[i][j] + bs;
      else
        Y[((size_t)b * M + m) * 256 + o] = acc[i][j] + bs;
    }
  }
}

// ---------------------------------------------------------------------------
// Depthwise 5x5 s2 conv + bias + LayerNorm(DH) + exact GELU + offset proj +
// grid clamp + bilinear sample of kv. One thread per (bh, n).
// Writes kvs[(bh*32+c)*576 + n]  (== (B,256,576) contiguous).
// ---------------------------------------------------------------------------
__global__ __launch_bounds__(256) void dw_sample_kernel(
    const float* __restrict__ q, const float* __restrict__ kv,
    const float* __restrict__ w_dw, const float* __restrict__ b_dw,
    const float* __restrict__ ln_w, const float* __restrict__ ln_b,
    const float* __restrict__ w_off, float* __restrict__ kvs) {
  __shared__ float s_wdw[DH * 25];
  __shared__ float s_bdw[DH], s_lnw[DH], s_lnb[DH], s_woff[2 * DH];
  const int tid = threadIdx.x;
  for (int i = tid; i < DH * 25; i += 256) s_wdw[i] = w_dw[i];
  if (tid < DH) { s_bdw[tid] = b_dw[tid]; s_lnw[tid] = ln_w[tid]; s_lnb[tid] = ln_b[tid]; }
  if (tid < 2 * DH) s_woff[tid] = w_off[tid];
  __syncthreads();

  const int gid = blockIdx.x * 256 + tid;  // [0, 64*576)
  const int bh = gid / NN;
  const int n = gid - bh * NN;
  const int yk = n / WK, xk = n - yk * WK;

  const float* qb = q + (size_t)bh * DH * HW;
  float t[DH];
#pragma unroll
  for (int c = 0; c < DH; c++) t[c] = s_bdw[c];

  const int y0r = yk * 2 - 2, x0r = xk * 2 - 2;
  for (int dy = 0; dy < 5; dy++) {
    int y = y0r + dy;
    if (y < 0 || y >= HH) continue;
    for (int dx = 0; dx < 5; dx++) {
      int x = x0r + dx;
      if (x < 0 || x >= WW) continue;
      int off = y * WW + x;
      int widx = dy * 5 + dx;
#pragma unroll
      for (int c = 0; c < DH; c++)
        t[c] += s_wdw[c * 25 + widx] * qb[c * HW + off];
    }
  }

  // LayerNorm over channels
  float mu = 0.f;
#pragma unroll
  for (int c = 0; c < DH; c++) mu += t[c];
  mu *= (1.0f / DH);
  float var = 0.f;
#pragma unroll
  for (int c = 0; c < DH; c++) { float d = t[c] - mu; var += d * d; }
  var *= (1.0f / DH);
  float rstd = rsqrtf(var + EPSF);

  float o0 = 0.f, o1 = 0.f;
#pragma unroll
  for (int c = 0; c < DH; c++) {
    float xn = (t[c] - mu) * rstd * s_lnw[c] + s_lnb[c];
    float g = 0.5f * xn * (1.0f + erff(xn * 0.70710678118654752f));
    o0 += s_woff[c] * g;
    o1 += s_woff[DH + c] * g;
  }

  const float ref_y = (0.5f + (float)yk) / 23.0f * 2.0f - 1.0f;
  const float ref_x = (0.5f + (float)xk) / 23.0f * 2.0f - 1.0f;
  float py = fminf(fmaxf(o0 + ref_y, -1.0f), 1.0f);
  float px = fminf(fmaxf(o1 + ref_x, -1.0f), 1.0f);

  float gx = (px + 1.0f) * 0.5f * 47.0f;
  float gy = (py + 1.0f) * 0.5f * 47.0f;
  float x0f = floorf(gx), y0f = floorf(gy);
  float wx = gx - x0f, wy = gy - y0f;
  int x0 = (int)x0f, y0 = (int)y0f;
  int x0i = min(max(x0, 0), WW - 1);
  int x1i = min(max(x0 + 1, 0), WW - 1);
  int y0i = min(max(y0, 0), HH - 1);
  int y1i = min(max(y0 + 1, 0), HH - 1);
  float w00 = (1.f - wx) * (1.f - wy);
  float w01 = wx * (1.f - wy);
  float w10 = (1.f - wx) * wy;
  float w11 = wx * wy;
  int i00 = y0i * WW + x0i, i01 = y0i * WW + x1i;
  int i10 = y1i * WW + x0i, i11 = y1i * WW + x1i;

  const float* kvb = kv + (size_t)bh * DH * HW;
#pragma unroll
  for (int c = 0; c < DH; c++) {
    const float* p = kvb + (size_t)c * HW;
    float val = w00 * p[i00] + w01 * p[i01] + w10 * p[i10] + w11 * p[i11];
    kvs[((size_t)bh * DH + c) * NN + n] = val;
  }
}

// ---------------------------------------------------------------------------
// Attention: 1 thread per (bh, m). Online softmax over n=576.
// kT/vT layout: (B, 576, 256), head slice contiguous 32 floats.
// Writes output in-place over q (each q column read only by its own thread).
// ---------------------------------------------------------------------------
__global__ __launch_bounds__(256) void attn_kernel(const float* __restrict__ q,
                                                   const float* __restrict__ kT,
                                                   const float* __restrict__ vT,
                                                   float* __restrict__ outp) {
  const int bh = blockIdx.y;
  const int m = blockIdx.x * 256 + threadIdx.x;
  const int b = bh >> 3, head = bh & 7;

  const float* qb = q + (size_t)bh * DH * HW + m;
  float qr[DH];
#pragma unroll
  for (int c = 0; c < DH; c++) qr[c] = qb[(size_t)c * HW];

  const float* kb = kT + (size_t)b * NN * 256 + head * DH;
  const float* vb = vT + (size_t)b * NN * 256 + head * DH;

  float acc[DH] = {};
  float mx = -1e30f, denom = 0.f;

  for (int n = 0; n < NN; n++) {
    const float4* kp = (const float4*)(kb + (size_t)n * 256);
    float s = 0.f;
#pragma unroll
    for (int c4 = 0; c4 < 8; c4++) {
      float4 k4 = kp[c4];
      s += qr[c4 * 4 + 0] * k4.x + qr[c4 * 4 + 1] * k4.y +
           qr[c4 * 4 + 2] * k4.z + qr[c4 * 4 + 3] * k4.w;
    }
    s *= SCALE;
    if (s > mx) {
      float corr = __expf(mx - s);
      denom *= corr;
#pragma unroll
      for (int c = 0; c < DH; c++) acc[c] *= corr;
      mx = s;
    }
    float p = __expf(s - mx);
    denom += p;
    const float4* vp = (const float4*)(vb + (size_t)n * 256);
#pragma unroll
    for (int c4 = 0; c4 < 8; c4++) {
      float4 v4 = vp[c4];
      acc[c4 * 4 + 0] += p * v4.x;
      acc[c4 * 4 + 1] += p * v4.y;
      acc[c4 * 4 + 2] += p * v4.z;
      acc[c4 * 4 + 3] += p * v4.w;
    }
  }

  float inv = 1.0f / denom;
  float* ob = outp + (size_t)bh * DH * HW + m;
#pragma unroll
  for (int c = 0; c < DH; c++) ob[(size_t)c * HW] = acc[c] * inv;
}

// ---------------------------------------------------------------------------
extern "C" void kernel_launch(void* const* d_in, const int* in_sizes, int n_in,
                              void* d_out, int out_size, void* d_ws, size_t ws_size,
                              hipStream_t stream) {
  const float* x    = (const float*)d_in[0];
  const float* kv   = (const float*)d_in[1];
  const float* wq   = (const float*)d_in[2];
  const float* bq   = (const float*)d_in[3];
  const float* wk   = (const float*)d_in[4];
  const float* bk   = (const float*)d_in[5];
  const float* wv   = (const float*)d_in[6];
  const float* bv   = (const float*)d_in[7];
  const float* w_dw = (const float*)d_in[8];
  const float* b_dw = (const float*)d_in[9];
  const float* ln_w = (const float*)d_in[10];
  const float* ln_b = (const float*)d_in[11];
  const float* w_off= (const float*)d_in[12];
  const float* wo   = (const float*)d_in[13];
  const float* bo   = (const float*)d_in[14];
  float* out = (float*)d_out;
  float* ws = (float*)d_ws;

  // workspace layout (floats)
  float* q   = ws;                      // 64*32*2304 = 4718592 (reused as attn out)
  float* kvs = ws + 4718592;            // 8*256*576  = 1179648
  float* kT  = ws + 5898240;            // 8*576*256  = 1179648
  float* vT  = ws + 7077888;            // 8*576*256  = 1179648
  // total 8257536 floats = 33.0 MB

  dim3 blk(256);
  // q = wq @ x + bq : (8, 256, 2304)
  gemm_bias<false><<<dim3(HW / TM, 256 / TO, BB), blk, 0, stream>>>(wq, bq, x, q, HW);
  // depthwise conv + LN + GELU + offsets + bilinear sample -> kvs (8,256,576)
  dw_sample_kernel<<<dim3(BH * NN / 256), blk, 0, stream>>>(q, kv, w_dw, b_dw, ln_w,
                                                            ln_b, w_off, kvs);
  // k,v (transposed store: (8,576,256))
  gemm_bias<true><<<dim3(NN / TM, 256 / TO, BB), blk, 0, stream>>>(wk, bk, kvs, kT, NN);
  gemm_bias<true><<<dim3(NN / TM, 256 / TO, BB), blk, 0, stream>>>(wv, bv, kvs, vT, NN);
  // attention, writes back into q
  attn_kernel<<<dim3(HW / 256, BH), blk, 0, stream>>>(q, kT, vT, q);
  // out = wo @ attn_out + bo
  gemm_bias<false><<<dim3(HW / TM, 256 / TO, BB), blk, 0, stream>>>(wo, bo, q, out, HW);
}

// Round 2
// 338.114 us; speedup vs baseline: 2.3879x; 2.3879x over previous
//
#include <hip/hip_runtime.h>
#include <hip/hip_bf16.h>
#include <cstddef>

// Problem constants
#define BB 8
#define DIM 256
#define HH 48
#define WW 48
#define HW 2304        // 48*48
#define HEADS 8
#define DH 32
#define BH 64          // B*HEADS
#define HK 24
#define WK 24
#define NN 576         // HK*WK
#define SCALE 0.17677669529663687f
#define EPSF 1e-5f

typedef __attribute__((ext_vector_type(8))) short short8;
typedef __attribute__((ext_vector_type(4))) float f32x4;

static __device__ inline short f2bf_s(float f) {
  __hip_bfloat16 h = __float2bfloat16(f);
  return *reinterpret_cast<short*>(&h);
}

template <typename T> __device__ inline T cvt_out(float v);
template <> __device__ inline float cvt_out<float>(float v) { return v; }
template <> __device__ inline __hip_bfloat16 cvt_out<__hip_bfloat16>(float v) {
  return __float2bfloat16(v);
}

// ---------------------------------------------------------------------------
// Per-batch 1x1-conv GEMM: Y[b](o,m) = sum_c W[o,c] * X[b](c,m) + bias[o]
// O = C = 256. TRANS=false: Y[b,o,m];  TRANS=true: Y[b,m,o]. OT = out dtype.
// ---------------------------------------------------------------------------
#define TO 64
#define TM 64
#define TKc 16

template <bool TRANS, typename OT>
__global__ __launch_bounds__(256) void gemm_bias(const float* __restrict__ Wt,
                                                 const float* __restrict__ bias,
                                                 const float* __restrict__ X,
                                                 OT* __restrict__ Y, int M) {
  __shared__ float As[TKc][TO + 4];
  __shared__ float Bs[TKc][TM + 4];
  const int b = blockIdx.z;
  const int oBase = blockIdx.y * TO;
  const int mBase = blockIdx.x * TM;
  const int tid = threadIdx.x;
  const int tx = tid & 15;   // -> m
  const int ty = tid >> 4;   // -> o
  const float* Xb = X + (size_t)b * 256 * (size_t)M;
  float acc[4][4] = {};

  for (int k0 = 0; k0 < 256; k0 += TKc) {
#pragma unroll
    for (int i = 0; i < 4; i++) {
      int idx = tid + i * 256;
      int o = idx >> 4, cc = idx & 15;
      As[cc][o] = Wt[(size_t)(oBase + o) * 256 + k0 + cc];
    }
#pragma unroll
    for (int i = 0; i < 4; i++) {
      int idx = tid + i * 256;
      int cc = idx >> 6, mm = idx & 63;
      Bs[cc][mm] = Xb[(size_t)(k0 + cc) * M + mBase + mm];
    }
    __syncthreads();
#pragma unroll
    for (int kc = 0; kc < TKc; kc++) {
      float a0 = As[kc][ty * 4 + 0];
      float a1 = As[kc][ty * 4 + 1];
      float a2 = As[kc][ty * 4 + 2];
      float a3 = As[kc][ty * 4 + 3];
      float b0 = Bs[kc][tx * 4 + 0];
      float b1 = Bs[kc][tx * 4 + 1];
      float b2 = Bs[kc][tx * 4 + 2];
      float b3 = Bs[kc][tx * 4 + 3];
      acc[0][0] += a0 * b0; acc[0][1] += a0 * b1; acc[0][2] += a0 * b2; acc[0][3] += a0 * b3;
      acc[1][0] += a1 * b0; acc[1][1] += a1 * b1; acc[1][2] += a1 * b2; acc[1][3] += a1 * b3;
      acc[2][0] += a2 * b0; acc[2][1] += a2 * b1; acc[2][2] += a2 * b2; acc[2][3] += a2 * b3;
      acc[3][0] += a3 * b0; acc[3][1] += a3 * b1; acc[3][2] += a3 * b2; acc[3][3] += a3 * b3;
    }
    __syncthreads();
  }

#pragma unroll
  for (int i = 0; i < 4; i++) {
    int o = oBase + ty * 4 + i;
    float bs = bias[o];
#pragma unroll
    for (int j = 0; j < 4; j++) {
      int m = mBase + tx * 4 + j;
      if (!TRANS)
        Y[((size_t)b * 256 + o) * M + m] = cvt_out<OT>(acc[i][j] + bs);
      else
        Y[((size_t)b * M + m) * 256 + o] = cvt_out<OT>(acc[i][j] + bs);
    }
  }
}

// ---------------------------------------------------------------------------
// wo GEMM reading bf16 attention output in [b][m][256] layout.
// ---------------------------------------------------------------------------
__global__ __launch_bounds__(256) void gemm_bias_xt(const float* __restrict__ Wt,
                                                    const float* __restrict__ bias,
                                                    const __hip_bfloat16* __restrict__ X,
                                                    float* __restrict__ Y, int M) {
  __shared__ float As[TKc][TO + 4];
  __shared__ float Bs[TKc][TM + 4];
  const int b = blockIdx.z;
  const int oBase = blockIdx.y * TO;
  const int mBase = blockIdx.x * TM;
  const int tid = threadIdx.x;
  const int tx = tid & 15;
  const int ty = tid >> 4;
  const __hip_bfloat16* Xb = X + (size_t)b * (size_t)M * 256;
  float acc[4][4] = {};

  for (int k0 = 0; k0 < 256; k0 += TKc) {
#pragma unroll
    for (int i = 0; i < 4; i++) {
      int idx = tid + i * 256;
      int o = idx >> 4, cc = idx & 15;
      As[cc][o] = Wt[(size_t)(oBase + o) * 256 + k0 + cc];
    }
#pragma unroll
    for (int i = 0; i < 4; i++) {
      int idx = tid + i * 256;
      int cc = idx & 15, mm = idx >> 4;
      Bs[cc][mm] = __bfloat162float(Xb[(size_t)(mBase + mm) * 256 + k0 + cc]);
    }
    __syncthreads();
#pragma unroll
    for (int kc = 0; kc < TKc; kc++) {
      float a0 = As[kc][ty * 4 + 0];
      float a1 = As[kc][ty * 4 + 1];
      float a2 = As[kc][ty * 4 + 2];
      float a3 = As[kc][ty * 4 + 3];
      float b0 = Bs[kc][tx * 4 + 0];
      float b1 = Bs[kc][tx * 4 + 1];
      float b2 = Bs[kc][tx * 4 + 2];
      float b3 = Bs[kc][tx * 4 + 3];
      acc[0][0] += a0 * b0; acc[0][1] += a0 * b1; acc[0][2] += a0 * b2; acc[0][3] += a0 * b3;
      acc[1][0] += a1 * b0; acc[1][1] += a1 * b1; acc[1][2] += a1 * b2; acc[1][3] += a1 * b3;
      acc[2][0] += a2 * b0; acc[2][1] += a2 * b1; acc[2][2] += a2 * b2; acc[2][3] += a2 * b3;
      acc[3][0] += a3 * b0; acc[3][1] += a3 * b1; acc[3][2] += a3 * b2; acc[3][3] += a3 * b3;
    }
    __syncthreads();
  }

#pragma unroll
  for (int i = 0; i < 4; i++) {
    int o = oBase + ty * 4 + i;
    float bs = bias[o];
#pragma unroll
    for (int j = 0; j < 4; j++) {
      int m = mBase + tx * 4 + j;
      Y[((size_t)b * 256 + o) * M + m] = acc[i][j] + bs;
    }
  }
}

// ---------------------------------------------------------------------------
// Depthwise 5x5 s2 conv + bias + LN + exact GELU + offset proj + clamp +
// bilinear sample of kv. One thread per (bh, n). Writes kvs (B,256,576) fp32.
// ---------------------------------------------------------------------------
__global__ __launch_bounds__(256) void dw_sample_kernel(
    const float* __restrict__ q, const float* __restrict__ kv,
    const float* __restrict__ w_dw, const float* __restrict__ b_dw,
    const float* __restrict__ ln_w, const float* __restrict__ ln_b,
    const float* __restrict__ w_off, float* __restrict__ kvs) {
  __shared__ float s_wdw[DH * 25];
  __shared__ float s_bdw[DH], s_lnw[DH], s_lnb[DH], s_woff[2 * DH];
  const int tid = threadIdx.x;
  for (int i = tid; i < DH * 25; i += 256) s_wdw[i] = w_dw[i];
  if (tid < DH) { s_bdw[tid] = b_dw[tid]; s_lnw[tid] = ln_w[tid]; s_lnb[tid] = ln_b[tid]; }
  if (tid < 2 * DH) s_woff[tid] = w_off[tid];
  __syncthreads();

  const int gid = blockIdx.x * 256 + tid;
  const int bh = gid / NN;
  const int n = gid - bh * NN;
  const int yk = n / WK, xk = n - yk * WK;

  const float* qb = q + (size_t)bh * DH * HW;
  float t[DH];
#pragma unroll
  for (int c = 0; c < DH; c++) t[c] = s_bdw[c];

  const int y0r = yk * 2 - 2, x0r = xk * 2 - 2;
  for (int dy = 0; dy < 5; dy++) {
    int y = y0r + dy;
    if (y < 0 || y >= HH) continue;
    for (int dx = 0; dx < 5; dx++) {
      int x = x0r + dx;
      if (x < 0 || x >= WW) continue;
      int off = y * WW + x;
      int widx = dy * 5 + dx;
#pragma unroll
      for (int c = 0; c < DH; c++)
        t[c] += s_wdw[c * 25 + widx] * qb[c * HW + off];
    }
  }

  float mu = 0.f;
#pragma unroll
  for (int c = 0; c < DH; c++) mu += t[c];
  mu *= (1.0f / DH);
  float var = 0.f;
#pragma unroll
  for (int c = 0; c < DH; c++) { float d = t[c] - mu; var += d * d; }
  var *= (1.0f / DH);
  float rstd = rsqrtf(var + EPSF);

  float o0 = 0.f, o1 = 0.f;
#pragma unroll
  for (int c = 0; c < DH; c++) {
    float xn = (t[c] - mu) * rstd * s_lnw[c] + s_lnb[c];
    float g = 0.5f * xn * (1.0f + erff(xn * 0.70710678118654752f));
    o0 += s_woff[c] * g;
    o1 += s_woff[DH + c] * g;
  }

  const float ref_y = (0.5f + (float)yk) / 23.0f * 2.0f - 1.0f;
  const float ref_x = (0.5f + (float)xk) / 23.0f * 2.0f - 1.0f;
  float py = fminf(fmaxf(o0 + ref_y, -1.0f), 1.0f);
  float px = fminf(fmaxf(o1 + ref_x, -1.0f), 1.0f);

  float gx = (px + 1.0f) * 0.5f * 47.0f;
  float gy = (py + 1.0f) * 0.5f * 47.0f;
  float x0f = floorf(gx), y0f = floorf(gy);
  float wx = gx - x0f, wy = gy - y0f;
  int x0 = (int)x0f, y0 = (int)y0f;
  int x0i = min(max(x0, 0), WW - 1);
  int x1i = min(max(x0 + 1, 0), WW - 1);
  int y0i = min(max(y0, 0), HH - 1);
  int y1i = min(max(y0 + 1, 0), HH - 1);
  float w00 = (1.f - wx) * (1.f - wy);
  float w01 = wx * (1.f - wy);
  float w10 = (1.f - wx) * wy;
  float w11 = wx * wy;
  int i00 = y0i * WW + x0i, i01 = y0i * WW + x1i;
  int i10 = y1i * WW + x0i, i11 = y1i * WW + x1i;

  const float* kvb = kv + (size_t)bh * DH * HW;
#pragma unroll
  for (int c = 0; c < DH; c++) {
    const float* p = kvb + (size_t)c * HW;
    float val = w00 * p[i00] + w01 * p[i01] + w10 * p[i10] + w11 * p[i11];
    kvs[((size_t)bh * DH + c) * NN + n] = val;
  }
}

// ---------------------------------------------------------------------------
// MFMA attention. Grid (36 m-tiles, 64 bh), 256 threads = 4 waves, each wave
// owns 16 m rows. Single pass: no max subtraction (|s| small), unnormalized
// exp accumulated through P.V with per-row denominators, scaled at the end.
// Kb: bf16 (B,576,256) ; Vb: bf16 (B,256,576) ; O out: bf16 (B,2304,256).
// ---------------------------------------------------------------------------
__global__ __launch_bounds__(256) void attn_mfma(const float* __restrict__ q,
                                                 const __hip_bfloat16* __restrict__ Kb,
                                                 const __hip_bfloat16* __restrict__ Vb,
                                                 __hip_bfloat16* __restrict__ O) {
  __shared__ short lds_p[4][16 * 40];  // per-wave P buffer, row stride 40 bf16 (80 B)
  const int tid = threadIdx.x;
  const int wave = tid >> 6;
  const int lane = tid & 63;
  const int quad = lane >> 4;
  const int l15 = lane & 15;
  const int bh = blockIdx.y;
  const int b = bh >> 3, head = bh & 7;
  const int mBase = blockIdx.x * 64 + wave * 16;

  // A-frag of Q (SCALE folded): A[m=l15][k=c=quad*8+j]
  short8 aq;
  {
    const float* qp = q + ((size_t)bh * DH + quad * 8) * HW + mBase + l15;
#pragma unroll
    for (int j = 0; j < 8; j++) aq[j] = f2bf_s(qp[(size_t)j * HW] * SCALE);
  }

  const short* kbase = (const short*)Kb + (size_t)b * NN * 256 + head * DH + quad * 8;
  const short* vbase = (const short*)Vb + (size_t)bh * DH * NN + quad * 8;

  f32x4 oacc0 = {0.f, 0.f, 0.f, 0.f};
  f32x4 oacc1 = {0.f, 0.f, 0.f, 0.f};
  float dsum[4] = {0.f, 0.f, 0.f, 0.f};
  short* myp = &lds_p[wave][0];

  for (int n0 = 0; n0 < NN; n0 += 32) {
    // K B-frags: B[k=c][n=l15], contiguous in c
    short8 kb0 = *(const short8*)(kbase + (size_t)(n0 + l15) * 256);
    short8 kb1 = *(const short8*)(kbase + (size_t)(n0 + 16 + l15) * 256);
    f32x4 z = {0.f, 0.f, 0.f, 0.f};
    f32x4 s0 = __builtin_amdgcn_mfma_f32_16x16x32_bf16(aq, kb0, z, 0, 0, 0);
    f32x4 s1 = __builtin_amdgcn_mfma_f32_16x16x32_bf16(aq, kb1, z, 0, 0, 0);
    // exp, denom accumulate, P -> LDS (C-layout: row m=quad*4+r, col n=l15)
#pragma unroll
    for (int r = 0; r < 4; r++) {
      float p0 = __expf(s0[r]);
      float p1 = __expf(s1[r]);
      dsum[r] += p0 + p1;
      int row = quad * 4 + r;
      myp[row * 40 + l15] = f2bf_s(p0);
      myp[row * 40 + 16 + l15] = f2bf_s(p1);
    }
    // P A-frag: A[m=l15][k=n=quad*8+j] (contiguous, 16B-aligned)
    short8 pa = *(const short8*)(myp + l15 * 40 + quad * 8);
    // V B-frags: B[k=n][c=l15], contiguous in n
    short8 vb0 = *(const short8*)(vbase + (size_t)l15 * NN + n0);
    short8 vb1 = *(const short8*)(vbase + (size_t)(16 + l15) * NN + n0);
    oacc0 = __builtin_amdgcn_mfma_f32_16x16x32_bf16(pa, vb0, oacc0, 0, 0, 0);
    oacc1 = __builtin_amdgcn_mfma_f32_16x16x32_bf16(pa, vb1, oacc1, 0, 0, 0);
  }

  // reduce denominators across the 16 lanes of each quad
#pragma unroll
  for (int mask = 1; mask <= 8; mask <<= 1) {
#pragma unroll
    for (int r = 0; r < 4; r++) dsum[r] += __shfl_xor(dsum[r], mask);
  }

  // store O[b][m][head*32 + c] bf16; rows m = mBase + quad*4 + r
  __hip_bfloat16* ob = O + ((size_t)b * HW + mBase) * 256 + head * DH + l15;
#pragma unroll
  for (int r = 0; r < 4; r++) {
    float inv = 1.0f / dsum[r];
    int m = quad * 4 + r;
    ob[(size_t)m * 256] = __float2bfloat16(oacc0[r] * inv);
    ob[(size_t)m * 256 + 16] = __float2bfloat16(oacc1[r] * inv);
  }
}

// ---------------------------------------------------------------------------
extern "C" void kernel_launch(void* const* d_in, const int* in_sizes, int n_in,
                              void* d_out, int out_size, void* d_ws, size_t ws_size,
                              hipStream_t stream) {
  const float* x    = (const float*)d_in[0];
  const float* kv   = (const float*)d_in[1];
  const float* wq   = (const float*)d_in[2];
  const float* bq   = (const float*)d_in[3];
  const float* wk   = (const float*)d_in[4];
  const float* bk   = (const float*)d_in[5];
  const float* wv   = (const float*)d_in[6];
  const float* bv   = (const float*)d_in[7];
  const float* w_dw = (const float*)d_in[8];
  const float* b_dw = (const float*)d_in[9];
  const float* ln_w = (const float*)d_in[10];
  const float* ln_b = (const float*)d_in[11];
  const float* w_off= (const float*)d_in[12];
  const float* wo   = (const float*)d_in[13];
  const float* bo   = (const float*)d_in[14];
  float* out = (float*)d_out;
  float* ws = (float*)d_ws;

  // workspace layout (float slots)
  float* q   = ws;                               // 64*32*2304 = 4718592 f
  float* kvs = ws + 4718592;                     // 8*256*576  = 1179648 f
  __hip_bfloat16* Kb = (__hip_bfloat16*)(ws + 5898240);  // 8*576*256 bf16 = 589824 f
  __hip_bfloat16* Vb = (__hip_bfloat16*)(ws + 6488064);  // 8*256*576 bf16 = 589824 f
  __hip_bfloat16* O  = (__hip_bfloat16*)(ws + 7077888);  // 8*2304*256 bf16 = 589824 f
  // total 7667712 floats = 30.7 MB

  dim3 blk(256);
  // q = wq @ x + bq : fp32 (8,256,2304)
  gemm_bias<false, float><<<dim3(HW / TM, 256 / TO, BB), blk, 0, stream>>>(wq, bq, x, q, HW);
  // offsets + bilinear sample -> kvs fp32 (8,256,576)
  dw_sample_kernel<<<dim3(BH * NN / 256), blk, 0, stream>>>(q, kv, w_dw, b_dw, ln_w,
                                                            ln_b, w_off, kvs);
  // K bf16 (8,576,256), V bf16 (8,256,576)
  gemm_bias<true, __hip_bfloat16><<<dim3(NN / TM, 256 / TO, BB), blk, 0, stream>>>(wk, bk, kvs, Kb, NN);
  gemm_bias<false, __hip_bfloat16><<<dim3(NN / TM, 256 / TO, BB), blk, 0, stream>>>(wv, bv, kvs, Vb, NN);
  // MFMA attention -> O bf16 (8,2304,256)
  attn_mfma<<<dim3(HW / 64, BH), blk, 0, stream>>>(q, Kb, Vb, O);
  // out = wo @ O + bo : fp32
  gemm_bias_xt<<<dim3(HW / TM, 256 / TO, BB), blk, 0, stream>>>(wo, bo, O, out, HW);
}

// Round 3
// 337.611 us; speedup vs baseline: 2.3914x; 1.0015x over previous
//
#include <hip/hip_runtime.h>
#include <hip/hip_bf16.h>
#include <cstddef>

// Problem constants
#define BB 8
#define DIM 256
#define HH 48
#define WW 48
#define HW 2304        // 48*48
#define HEADS 8
#define DH 32
#define BH 64          // B*HEADS
#define HK 24
#define WK 24
#define NN 576         // HK*WK
#define SCALE 0.17677669529663687f
#define EPSF 1e-5f

typedef __attribute__((ext_vector_type(8))) short short8;
typedef __attribute__((ext_vector_type(4))) float f32x4;

static __device__ inline short f2bf_s(float f) {
  __hip_bfloat16 h = __float2bfloat16(f);
  return *reinterpret_cast<short*>(&h);
}
static __device__ inline unsigned int pkbf(float a, float b) {
  return (unsigned int)(unsigned short)f2bf_s(a) |
         ((unsigned int)(unsigned short)f2bf_s(b) << 16);
}

template <typename T> __device__ inline T cvt_out(float v);
template <> __device__ inline float cvt_out<float>(float v) { return v; }
template <> __device__ inline __hip_bfloat16 cvt_out<__hip_bfloat16>(float v) {
  return __float2bfloat16(v);
}

// ---------------------------------------------------------------------------
// fp32 1x1-conv GEMM (used for q, k, v). Y[b](o,m) = W[o,c]X[b](c,m)+bias[o].
// TRANS=false: Y[b,o,m]; TRANS=true: Y[b,m,o]. OT = output dtype.
// ---------------------------------------------------------------------------
#define TO 64
#define TM 64
#define TKc 16

template <bool TRANS, typename OT>
__global__ __launch_bounds__(256) void gemm_bias(const float* __restrict__ Wt,
                                                 const float* __restrict__ bias,
                                                 const float* __restrict__ X,
                                                 OT* __restrict__ Y, int M) {
  __shared__ float As[TKc][TO + 4];
  __shared__ float Bs[TKc][TM + 4];
  const int b = blockIdx.z;
  const int oBase = blockIdx.y * TO;
  const int mBase = blockIdx.x * TM;
  const int tid = threadIdx.x;
  const int tx = tid & 15;   // -> m
  const int ty = tid >> 4;   // -> o
  const float* Xb = X + (size_t)b * 256 * (size_t)M;
  float acc[4][4] = {};

  for (int k0 = 0; k0 < 256; k0 += TKc) {
#pragma unroll
    for (int i = 0; i < 4; i++) {
      int idx = tid + i * 256;
      int o = idx >> 4, cc = idx & 15;
      As[cc][o] = Wt[(size_t)(oBase + o) * 256 + k0 + cc];
    }
#pragma unroll
    for (int i = 0; i < 4; i++) {
      int idx = tid + i * 256;
      int cc = idx >> 6, mm = idx & 63;
      Bs[cc][mm] = Xb[(size_t)(k0 + cc) * M + mBase + mm];
    }
    __syncthreads();
#pragma unroll
    for (int kc = 0; kc < TKc; kc++) {
      float a0 = As[kc][ty * 4 + 0];
      float a1 = As[kc][ty * 4 + 1];
      float a2 = As[kc][ty * 4 + 2];
      float a3 = As[kc][ty * 4 + 3];
      float b0 = Bs[kc][tx * 4 + 0];
      float b1 = Bs[kc][tx * 4 + 1];
      float b2 = Bs[kc][tx * 4 + 2];
      float b3 = Bs[kc][tx * 4 + 3];
      acc[0][0] += a0 * b0; acc[0][1] += a0 * b1; acc[0][2] += a0 * b2; acc[0][3] += a0 * b3;
      acc[1][0] += a1 * b0; acc[1][1] += a1 * b1; acc[1][2] += a1 * b2; acc[1][3] += a1 * b3;
      acc[2][0] += a2 * b0; acc[2][1] += a2 * b1; acc[2][2] += a2 * b2; acc[2][3] += a2 * b3;
      acc[3][0] += a3 * b0; acc[3][1] += a3 * b1; acc[3][2] += a3 * b2; acc[3][3] += a3 * b3;
    }
    __syncthreads();
  }

#pragma unroll
  for (int i = 0; i < 4; i++) {
    int o = oBase + ty * 4 + i;
    float bs = bias[o];
#pragma unroll
    for (int j = 0; j < 4; j++) {
      int m = mBase + tx * 4 + j;
      if (!TRANS)
        Y[((size_t)b * 256 + o) * M + m] = cvt_out<OT>(acc[i][j] + bs);
      else
        Y[((size_t)b * M + m) * 256 + o] = cvt_out<OT>(acc[i][j] + bs);
    }
  }
}

// ---------------------------------------------------------------------------
// Split fp32 -> bf16 hi/lo pair (w = hi + lo to ~16 mantissa bits).
// ---------------------------------------------------------------------------
__global__ __launch_bounds__(256) void split_bf16(const float* __restrict__ w,
                                                  short* __restrict__ hi,
                                                  short* __restrict__ lo, int n) {
  int i = blockIdx.x * 256 + threadIdx.x;
  if (i < n) {
    float v = w[i];
    short h = f2bf_s(v);
    __hip_bfloat16 hb = *reinterpret_cast<__hip_bfloat16*>(&h);
    hi[i] = h;
    lo[i] = f2bf_s(v - __bfloat162float(hb));
  }
}

// ---------------------------------------------------------------------------
// Depthwise 5x5 s2 conv + bias + LN + exact GELU + offset proj + clamp +
// bilinear sample of kv. One thread per (bh, n). Writes kvs (B,256,576) fp32.
// ---------------------------------------------------------------------------
__global__ __launch_bounds__(256) void dw_sample_kernel(
    const float* __restrict__ q, const float* __restrict__ kv,
    const float* __restrict__ w_dw, const float* __restrict__ b_dw,
    const float* __restrict__ ln_w, const float* __restrict__ ln_b,
    const float* __restrict__ w_off, float* __restrict__ kvs) {
  __shared__ float s_wdw[DH * 25];
  __shared__ float s_bdw[DH], s_lnw[DH], s_lnb[DH], s_woff[2 * DH];
  const int tid = threadIdx.x;
  for (int i = tid; i < DH * 25; i += 256) s_wdw[i] = w_dw[i];
  if (tid < DH) { s_bdw[tid] = b_dw[tid]; s_lnw[tid] = ln_w[tid]; s_lnb[tid] = ln_b[tid]; }
  if (tid < 2 * DH) s_woff[tid] = w_off[tid];
  __syncthreads();

  const int gid = blockIdx.x * 256 + tid;
  const int bh = gid / NN;
  const int n = gid - bh * NN;
  const int yk = n / WK, xk = n - yk * WK;

  const float* qb = q + (size_t)bh * DH * HW;
  float t[DH];
#pragma unroll
  for (int c = 0; c < DH; c++) t[c] = s_bdw[c];

  const int y0r = yk * 2 - 2, x0r = xk * 2 - 2;
  for (int dy = 0; dy < 5; dy++) {
    int y = y0r + dy;
    if (y < 0 || y >= HH) continue;
    for (int dx = 0; dx < 5; dx++) {
      int x = x0r + dx;
      if (x < 0 || x >= WW) continue;
      int off = y * WW + x;
      int widx = dy * 5 + dx;
#pragma unroll
      for (int c = 0; c < DH; c++)
        t[c] += s_wdw[c * 25 + widx] * qb[c * HW + off];
    }
  }

  float mu = 0.f;
#pragma unroll
  for (int c = 0; c < DH; c++) mu += t[c];
  mu *= (1.0f / DH);
  float var = 0.f;
#pragma unroll
  for (int c = 0; c < DH; c++) { float d = t[c] - mu; var += d * d; }
  var *= (1.0f / DH);
  float rstd = rsqrtf(var + EPSF);

  float o0 = 0.f, o1 = 0.f;
#pragma unroll
  for (int c = 0; c < DH; c++) {
    float xn = (t[c] - mu) * rstd * s_lnw[c] + s_lnb[c];
    float g = 0.5f * xn * (1.0f + erff(xn * 0.70710678118654752f));
    o0 += s_woff[c] * g;
    o1 += s_woff[DH + c] * g;
  }

  const float ref_y = (0.5f + (float)yk) / 23.0f * 2.0f - 1.0f;
  const float ref_x = (0.5f + (float)xk) / 23.0f * 2.0f - 1.0f;
  float py = fminf(fmaxf(o0 + ref_y, -1.0f), 1.0f);
  float px = fminf(fmaxf(o1 + ref_x, -1.0f), 1.0f);

  float gx = (px + 1.0f) * 0.5f * 47.0f;
  float gy = (py + 1.0f) * 0.5f * 47.0f;
  float x0f = floorf(gx), y0f = floorf(gy);
  float wx = gx - x0f, wy = gy - y0f;
  int x0 = (int)x0f, y0 = (int)y0f;
  int x0i = min(max(x0, 0), WW - 1);
  int x1i = min(max(x0 + 1, 0), WW - 1);
  int y0i = min(max(y0, 0), HH - 1);
  int y1i = min(max(y0 + 1, 0), HH - 1);
  float w00 = (1.f - wx) * (1.f - wy);
  float w01 = wx * (1.f - wy);
  float w10 = (1.f - wx) * wy;
  float w11 = wx * wy;
  int i00 = y0i * WW + x0i, i01 = y0i * WW + x1i;
  int i10 = y1i * WW + x0i, i11 = y1i * WW + x1i;

  const float* kvb = kv + (size_t)bh * DH * HW;
#pragma unroll
  for (int c = 0; c < DH; c++) {
    const float* p = kvb + (size_t)c * HW;
    float val = w00 * p[i00] + w01 * p[i01] + w10 * p[i10] + w11 * p[i11];
    kvs[((size_t)bh * DH + c) * NN + n] = val;
  }
}

// ---------------------------------------------------------------------------
// MFMA attention v3: compute S^T via mfma(A=K, B=Q), exp in-register,
// transpose P to A-layout with 8x ds_bpermute + cndmask (no LDS array).
// Kb: bf16 (B,576,256); Vb: bf16 (B,256,576); O: bf16 (B,2304,256).
// Grid (36 m-tiles, 64 bh), 4 waves/block, 16 m rows per wave.
// ---------------------------------------------------------------------------
__global__ __launch_bounds__(256) void attn_mfma(const float* __restrict__ q,
                                                 const __hip_bfloat16* __restrict__ Kb,
                                                 const __hip_bfloat16* __restrict__ Vb,
                                                 __hip_bfloat16* __restrict__ O) {
  const int tid = threadIdx.x;
  const int wave = tid >> 6;
  const int lane = tid & 63;
  const int quad = lane >> 4;
  const int l15 = lane & 15;
  const int bh = blockIdx.y;
  const int b = bh >> 3, head = bh & 7;
  const int mBase = blockIdx.x * 64 + wave * 16;

  // Q B-frag: B[k=c=quad*8+j][col=m=l15], SCALE folded.
  short8 bq;
  {
    const float* qp = q + ((size_t)bh * DH + quad * 8) * HW + mBase + l15;
#pragma unroll
    for (int j = 0; j < 8; j++) bq[j] = f2bf_s(qp[(size_t)j * HW] * SCALE);
  }

  const short* kbase = (const short*)Kb + (size_t)b * NN * 256 + head * DH + quad * 8;
  const short* vb0p = (const short*)Vb + (size_t)bh * DH * NN + (size_t)l15 * NN + quad * 8;
  const short* vb1p = vb0p + (size_t)16 * NN;

  // bpermute byte addresses: src lane = ((quad&1)*2 + (j'>>1))*16 + l15
  const int addrA = (((quad & 1) * 2) * 16 + l15) * 4;
  const int addrB = addrA + 64;
  const bool hiHalf = (quad >= 2);

  f32x4 oacc0 = {0.f, 0.f, 0.f, 0.f};
  f32x4 oacc1 = {0.f, 0.f, 0.f, 0.f};
  float dsum = 0.f;

  short8 ka0 = *(const short8*)(kbase + (size_t)l15 * 256);
  short8 ka1 = *(const short8*)(kbase + (size_t)(16 + l15) * 256);

  for (int nb = 0; nb < NN; nb += 32) {
    short8 va0 = *(const short8*)(vb0p + nb);
    short8 va1 = *(const short8*)(vb1p + nb);
    f32x4 z = {0.f, 0.f, 0.f, 0.f};
    // st[r] = S[m=l15][nb + quad*4 + r] (tile0), + 16 (tile1)
    f32x4 st0 = __builtin_amdgcn_mfma_f32_16x16x32_bf16(ka0, bq, z, 0, 0, 0);
    f32x4 st1 = __builtin_amdgcn_mfma_f32_16x16x32_bf16(ka1, bq, z, 0, 0, 0);
    if (nb + 32 < NN) {  // prefetch next K frags
      ka0 = *(const short8*)(kbase + (size_t)(nb + 32 + l15) * 256);
      ka1 = *(const short8*)(kbase + (size_t)(nb + 48 + l15) * 256);
    }
    float p0 = __expf(st0[0]), p1 = __expf(st0[1]);
    float p2 = __expf(st0[2]), p3 = __expf(st0[3]);
    float p4 = __expf(st1[0]), p5 = __expf(st1[1]);
    float p6 = __expf(st1[2]), p7 = __expf(st1[3]);
    dsum += ((p0 + p1) + (p2 + p3)) + ((p4 + p5) + (p6 + p7));
    unsigned int pk0 = pkbf(p0, p1);  // n = nb + quad*4 + {0,1}
    unsigned int pk1 = pkbf(p2, p3);  // n = nb + quad*4 + {2,3}
    unsigned int pk2 = pkbf(p4, p5);  // n = nb+16 + quad*4 + {0,1}
    unsigned int pk3 = pkbf(p6, p7);  // n = nb+16 + quad*4 + {2,3}
    // Assemble PV A-frag: pa slot j' holds pair n_local = quad*8 + 2j', +1.
    int lo0 = __builtin_amdgcn_ds_bpermute(addrA, (int)pk0);
    int hi0 = __builtin_amdgcn_ds_bpermute(addrA, (int)pk2);
    int lo1 = __builtin_amdgcn_ds_bpermute(addrA, (int)pk1);
    int hi1 = __builtin_amdgcn_ds_bpermute(addrA, (int)pk3);
    int lo2 = __builtin_amdgcn_ds_bpermute(addrB, (int)pk0);
    int hi2 = __builtin_amdgcn_ds_bpermute(addrB, (int)pk2);
    int lo3 = __builtin_amdgcn_ds_bpermute(addrB, (int)pk1);
    int hi3 = __builtin_amdgcn_ds_bpermute(addrB, (int)pk3);
    union { int i[4]; short8 v; } u;
    u.i[0] = hiHalf ? hi0 : lo0;
    u.i[1] = hiHalf ? hi1 : lo1;
    u.i[2] = hiHalf ? hi2 : lo2;
    u.i[3] = hiHalf ? hi3 : lo3;
    oacc0 = __builtin_amdgcn_mfma_f32_16x16x32_bf16(u.v, va0, oacc0, 0, 0, 0);
    oacc1 = __builtin_amdgcn_mfma_f32_16x16x32_bf16(u.v, va1, oacc1, 0, 0, 0);
  }

  // full denominator for m = l15
  dsum += __shfl_xor(dsum, 16);
  dsum += __shfl_xor(dsum, 32);

  // store O[b][m][head*32 + c]; PV output rows m = quad*4 + r, cols c = l15, 16+l15
  __hip_bfloat16* ob = O + ((size_t)b * HW + mBase) * 256 + head * DH + l15;
#pragma unroll
  for (int r = 0; r < 4; r++) {
    float dr = __shfl(dsum, quad * 4 + r);
    float inv = 1.0f / dr;
    ob[(size_t)(quad * 4 + r) * 256] = __float2bfloat16(oacc0[r] * inv);
    ob[(size_t)(quad * 4 + r) * 256 + 16] = __float2bfloat16(oacc1[r] * inv);
  }
}

// ---------------------------------------------------------------------------
// wo GEMM via MFMA with split-bf16 weights: out[b,o,m] = (Whi+Wlo)@O^T + bo.
// X = O bf16 (b, m, 256). Grid (36 m-tiles, 4 o-tiles, 8 b), 4 waves/block,
// wave w -> 16 o rows, 64 m cols.
// ---------------------------------------------------------------------------
__global__ __launch_bounds__(256) void wo_gemm_mfma(const short* __restrict__ Whi,
                                                    const short* __restrict__ Wlo,
                                                    const float* __restrict__ bias,
                                                    const short* __restrict__ X,
                                                    float* __restrict__ Y) {
  const int tid = threadIdx.x;
  const int wave = tid >> 6;
  const int lane = tid & 63;
  const int quad = lane >> 4;
  const int l15 = lane & 15;
  const int b = blockIdx.z;
  const int oBase = blockIdx.y * 64 + wave * 16;
  const int mBase = blockIdx.x * 64;

  const short* wh = Whi + (size_t)(oBase + l15) * 256 + quad * 8;
  const short* wl = Wlo + (size_t)(oBase + l15) * 256 + quad * 8;
  const short* xb = X + ((size_t)b * HW + mBase) * 256 + quad * 8;

  f32x4 acc[4] = {{0.f,0.f,0.f,0.f},{0.f,0.f,0.f,0.f},{0.f,0.f,0.f,0.f},{0.f,0.f,0.f,0.f}};

  for (int k = 0; k < 256; k += 32) {
    short8 ah = *(const short8*)(wh + k);
    short8 al = *(const short8*)(wl + k);
#pragma unroll
    for (int mt = 0; mt < 4; mt++) {
      short8 bx = *(const short8*)(xb + (size_t)(mt * 16 + l15) * 256 + k);
      acc[mt] = __builtin_amdgcn_mfma_f32_16x16x32_bf16(ah, bx, acc[mt], 0, 0, 0);
      acc[mt] = __builtin_amdgcn_mfma_f32_16x16x32_bf16(al, bx, acc[mt], 0, 0, 0);
    }
  }

#pragma unroll
  for (int r = 0; r < 4; r++) {
    int o = oBase + quad * 4 + r;
    float bs = bias[o];
    float* yrow = Y + ((size_t)b * 256 + o) * HW + mBase + l15;
#pragma unroll
    for (int mt = 0; mt < 4; mt++) {
      yrow[mt * 16] = acc[mt][r] + bs;
    }
  }
}

// ---------------------------------------------------------------------------
extern "C" void kernel_launch(void* const* d_in, const int* in_sizes, int n_in,
                              void* d_out, int out_size, void* d_ws, size_t ws_size,
                              hipStream_t stream) {
  const float* x    = (const float*)d_in[0];
  const float* kv   = (const float*)d_in[1];
  const float* wq   = (const float*)d_in[2];
  const float* bq   = (const float*)d_in[3];
  const float* wk   = (const float*)d_in[4];
  const float* bk   = (const float*)d_in[5];
  const float* wv   = (const float*)d_in[6];
  const float* bv   = (const float*)d_in[7];
  const float* w_dw = (const float*)d_in[8];
  const float* b_dw = (const float*)d_in[9];
  const float* ln_w = (const float*)d_in[10];
  const float* ln_b = (const float*)d_in[11];
  const float* w_off= (const float*)d_in[12];
  const float* wo   = (const float*)d_in[13];
  const float* bo   = (const float*)d_in[14];
  float* out = (float*)d_out;
  float* ws = (float*)d_ws;

  // workspace layout (float slots)
  float* q   = ws;                                        // 4718592 f
  float* kvs = ws + 4718592;                              // 1179648 f
  __hip_bfloat16* Kb = (__hip_bfloat16*)(ws + 5898240);   // 8*576*256 bf16
  __hip_bfloat16* Vb = (__hip_bfloat16*)(ws + 6488064);   // 8*256*576 bf16
  __hip_bfloat16* O  = (__hip_bfloat16*)(ws + 7077888);   // 8*2304*256 bf16 = 2359296 f
  short* Whi = (short*)(ws + 9437184);                    // 65536 bf16 = 32768 f
  short* Wlo = (short*)(ws + 9469952);                    // 65536 bf16 = 32768 f
  // total 9502720 f = 38.0 MB

  dim3 blk(256);
  // split wo into bf16 hi/lo
  split_bf16<<<dim3(256), blk, 0, stream>>>(wo, Whi, Wlo, 65536);
  // q = wq @ x + bq : fp32 (8,256,2304)
  gemm_bias<false, float><<<dim3(HW / TM, 256 / TO, BB), blk, 0, stream>>>(wq, bq, x, q, HW);
  // offsets + bilinear sample -> kvs fp32 (8,256,576)
  dw_sample_kernel<<<dim3(BH * NN / 256), blk, 0, stream>>>(q, kv, w_dw, b_dw, ln_w,
                                                            ln_b, w_off, kvs);
  // K bf16 (8,576,256), V bf16 (8,256,576)
  gemm_bias<true, __hip_bfloat16><<<dim3(NN / TM, 256 / TO, BB), blk, 0, stream>>>(wk, bk, kvs, Kb, NN);
  gemm_bias<false, __hip_bfloat16><<<dim3(NN / TM, 256 / TO, BB), blk, 0, stream>>>(wv, bv, kvs, Vb, NN);
  // MFMA attention -> O bf16 (8,2304,256)
  attn_mfma<<<dim3(HW / 64, BH), blk, 0, stream>>>(q, Kb, Vb, O);
  // out = wo @ O + bo via split-bf16 MFMA
  wo_gemm_mfma<<<dim3(HW / 64, 4, BB), blk, 0, stream>>>(Whi, Wlo, bo, (const short*)O, out);
}

// Round 5
// 270.789 us; speedup vs baseline: 2.9815x; 1.2468x over previous
//
#include <hip/hip_runtime.h>
#include <hip/hip_bf16.h>
#include <cstddef>

// Problem constants
#define BB 8
#define DIM 256
#define HH 48
#define WW 48
#define HW 2304        // 48*48
#define HEADS 8
#define DH 32
#define BH 64          // B*HEADS
#define HK 24
#define WK 24
#define NN 576         // HK*WK
#define SCALE 0.17677669529663687f
#define EPSF 1e-5f

typedef __attribute__((ext_vector_type(8))) short short8;
typedef __attribute__((ext_vector_type(4))) float f32x4;

static __device__ inline short f2bf_s(float f) {
  __hip_bfloat16 h = __float2bfloat16(f);
  return *reinterpret_cast<short*>(&h);
}

template <typename T> __device__ inline T cvt_out(float v);
template <> __device__ inline float cvt_out<float>(float v) { return v; }
template <> __device__ inline __hip_bfloat16 cvt_out<__hip_bfloat16>(float v) {
  return __float2bfloat16(v);
}

// pack two floats into bf16 pair (round-half-up): lo short = a, hi short = b
static __device__ inline unsigned pkrnd(float a, float b) {
  unsigned ua = __builtin_bit_cast(unsigned, a) + 0x8000u;
  unsigned ub = __builtin_bit_cast(unsigned, b) + 0x8000u;
  return __builtin_amdgcn_perm(ub, ua, 0x07060302);
}

// in-register split of 8 fp32 into bf16 hi/lo fragments (truncation split:
// hi = trunc16(x), lo = trunc16(x - hi); missing lo*lo term ~2^-16 rel)
static __device__ inline void split8(const float* xf, short8& bh, short8& bl) {
  union { unsigned u[4]; short8 v; } H, L;
#pragma unroll
  for (int p = 0; p < 4; p++) {
    float x0 = xf[2 * p], x1 = xf[2 * p + 1];
    unsigned u0 = __builtin_bit_cast(unsigned, x0) & 0xffff0000u;
    unsigned u1 = __builtin_bit_cast(unsigned, x1) & 0xffff0000u;
    float l0 = x0 - __builtin_bit_cast(float, u0);
    float l1 = x1 - __builtin_bit_cast(float, u1);
    H.u[p] = __builtin_amdgcn_perm(u1, u0, 0x07060302);
    L.u[p] = __builtin_amdgcn_perm(__builtin_bit_cast(unsigned, l1),
                                   __builtin_bit_cast(unsigned, l0), 0x07060302);
  }
  bh = H.v;
  bl = L.v;
}

// ---------------------------------------------------------------------------
// Split 4 weight matrices (each 65536 fp32) into bf16 hi/lo planes.
// Grid: 1024 blocks x 256; sel = blockIdx >> 8.
// ---------------------------------------------------------------------------
__global__ __launch_bounds__(256) void split4(
    const float* __restrict__ w0, const float* __restrict__ w1,
    const float* __restrict__ w2, const float* __restrict__ w3,
    short* __restrict__ h0, short* __restrict__ l0,
    short* __restrict__ h1, short* __restrict__ l1,
    short* __restrict__ h2, short* __restrict__ l2,
    short* __restrict__ h3, short* __restrict__ l3) {
  const float* srcs[4] = {w0, w1, w2, w3};
  short* his[4] = {h0, h1, h2, h3};
  short* los[4] = {l0, l1, l2, l3};
  int sel = blockIdx.x >> 8;
  int i = (blockIdx.x & 255) * 256 + threadIdx.x;
  float v = srcs[sel][i];
  unsigned u = __builtin_bit_cast(unsigned, v) & 0xffff0000u;
  float rem = v - __builtin_bit_cast(float, u);
  his[sel][i] = (short)(u >> 16);
  los[sel][i] = (short)(__builtin_bit_cast(unsigned, rem) >> 16);
}

// ---------------------------------------------------------------------------
// MFMA GEMM, A = W (o rows, split bf16), B = X fp32 c-major split in-register.
// Y[b,o,m] = (Wh+Wl)@(Xh+Xl) + bias. 1 wave per block: o-tile 32, m-tile 64.
// Grid: (M/64, 256/32, B). Used for q (OT=float, M=2304) and v (OT=bf16, M=576).
// ---------------------------------------------------------------------------
template <typename OT>
__global__ __launch_bounds__(64) void gemm_axf_mfma(const short* __restrict__ Wh,
                                                    const short* __restrict__ Wl,
                                                    const float* __restrict__ bias,
                                                    const float* __restrict__ X,
                                                    OT* __restrict__ Y, int M) {
  const int lane = threadIdx.x;
  const int quad = lane >> 4, l15 = lane & 15;
  const int b = blockIdx.z;
  const int oBase = blockIdx.y * 32;
  const int mBase = blockIdx.x * 64;
  const float* Xq = X + ((size_t)b * 256 + quad * 8) * M;

  f32x4 acc[2][4] = {};
  for (int kc = 0; kc < 256; kc += 32) {
    short8 ah0 = *(const short8*)(Wh + (size_t)(oBase + l15) * 256 + kc + quad * 8);
    short8 al0 = *(const short8*)(Wl + (size_t)(oBase + l15) * 256 + kc + quad * 8);
    short8 ah1 = *(const short8*)(Wh + (size_t)(oBase + 16 + l15) * 256 + kc + quad * 8);
    short8 al1 = *(const short8*)(Wl + (size_t)(oBase + 16 + l15) * 256 + kc + quad * 8);
#pragma unroll
    for (int mt = 0; mt < 4; mt++) {
      float xf[8];
      const float* xp = Xq + (size_t)kc * M + mBase + mt * 16 + l15;
#pragma unroll
      for (int j = 0; j < 8; j++) xf[j] = xp[(size_t)j * M];
      short8 bh, bl;
      split8(xf, bh, bl);
      acc[0][mt] = __builtin_amdgcn_mfma_f32_16x16x32_bf16(ah0, bh, acc[0][mt], 0, 0, 0);
      acc[0][mt] = __builtin_amdgcn_mfma_f32_16x16x32_bf16(al0, bh, acc[0][mt], 0, 0, 0);
      acc[0][mt] = __builtin_amdgcn_mfma_f32_16x16x32_bf16(ah0, bl, acc[0][mt], 0, 0, 0);
      acc[1][mt] = __builtin_amdgcn_mfma_f32_16x16x32_bf16(ah1, bh, acc[1][mt], 0, 0, 0);
      acc[1][mt] = __builtin_amdgcn_mfma_f32_16x16x32_bf16(al1, bh, acc[1][mt], 0, 0, 0);
      acc[1][mt] = __builtin_amdgcn_mfma_f32_16x16x32_bf16(ah1, bl, acc[1][mt], 0, 0, 0);
    }
  }

#pragma unroll
  for (int os = 0; os < 2; os++)
#pragma unroll
    for (int r = 0; r < 4; r++) {
      int o = oBase + os * 16 + quad * 4 + r;
      float bs = bias[o];
      OT* yp = Y + ((size_t)b * 256 + o) * M + mBase + l15;
#pragma unroll
      for (int mt = 0; mt < 4; mt++) yp[mt * 16] = cvt_out<OT>(acc[os][mt][r] + bs);
    }
}

// ---------------------------------------------------------------------------
// K GEMM producing K^T directly: Kb[b,n,o] = sum_c kvs[b,c,n]*Wk[o,c] + bk[o].
// D(n,o) = A(kvs^T, split in-register) . B(Wk^T, pre-split). 1 wave per block:
// n-tile 32, o-tile 64. Grid (576/32, 256/64, B).
// ---------------------------------------------------------------------------
__global__ __launch_bounds__(64) void k_gemm_mfma(const short* __restrict__ Wh,
                                                  const short* __restrict__ Wl,
                                                  const float* __restrict__ bias,
                                                  const float* __restrict__ X,
                                                  short* __restrict__ Y) {
  const int lane = threadIdx.x;
  const int quad = lane >> 4, l15 = lane & 15;
  const int b = blockIdx.z;
  const int nBase = blockIdx.x * 32;
  const int oBase = blockIdx.y * 64;
  const float* Xq = X + ((size_t)b * 256 + quad * 8) * NN;

  f32x4 acc[2][4] = {};
  for (int kc = 0; kc < 256; kc += 32) {
    short8 ah[2], al[2];
#pragma unroll
    for (int ns = 0; ns < 2; ns++) {
      float xf[8];
      const float* xp = Xq + (size_t)kc * NN + nBase + ns * 16 + l15;
#pragma unroll
      for (int j = 0; j < 8; j++) xf[j] = xp[(size_t)j * NN];
      split8(xf, ah[ns], al[ns]);
    }
#pragma unroll
    for (int ot = 0; ot < 4; ot++) {
      short8 bh = *(const short8*)(Wh + (size_t)(oBase + ot * 16 + l15) * 256 + kc + quad * 8);
      short8 bl = *(const short8*)(Wl + (size_t)(oBase + ot * 16 + l15) * 256 + kc + quad * 8);
#pragma unroll
      for (int ns = 0; ns < 2; ns++) {
        acc[ns][ot] = __builtin_amdgcn_mfma_f32_16x16x32_bf16(ah[ns], bh, acc[ns][ot], 0, 0, 0);
        acc[ns][ot] = __builtin_amdgcn_mfma_f32_16x16x32_bf16(al[ns], bh, acc[ns][ot], 0, 0, 0);
        acc[ns][ot] = __builtin_amdgcn_mfma_f32_16x16x32_bf16(ah[ns], bl, acc[ns][ot], 0, 0, 0);
      }
    }
  }

  float bs[4];
#pragma unroll
  for (int ot = 0; ot < 4; ot++) bs[ot] = bias[oBase + ot * 16 + l15];
#pragma unroll
  for (int ns = 0; ns < 2; ns++)
#pragma unroll
    for (int r = 0; r < 4; r++) {
      int n = nBase + ns * 16 + quad * 4 + r;
      short* yp = Y + ((size_t)b * NN + n) * 256 + oBase + l15;
#pragma unroll
      for (int ot = 0; ot < 4; ot++) yp[ot * 16] = f2bf_s(acc[ns][ot][r] + bs[ot]);
    }
}

// ---------------------------------------------------------------------------
// Depthwise 5x5 s2 conv + bias + LN + exact GELU + offset proj + clamp +
// bilinear sample of kv. One thread per (bh, n). Writes kvs (B,256,576) fp32.
// ---------------------------------------------------------------------------
__global__ __launch_bounds__(64) void dw_sample_kernel(
    const float* __restrict__ q, const float* __restrict__ kv,
    const float* __restrict__ w_dw, const float* __restrict__ b_dw,
    const float* __restrict__ ln_w, const float* __restrict__ ln_b,
    const float* __restrict__ w_off, float* __restrict__ kvs) {
  __shared__ float s_wdw[DH * 25];
  __shared__ float s_bdw[DH], s_lnw[DH], s_lnb[DH], s_woff[2 * DH];
  const int tid = threadIdx.x;
  for (int i = tid; i < DH * 25; i += 64) s_wdw[i] = w_dw[i];
  if (tid < DH) { s_bdw[tid] = b_dw[tid]; s_lnw[tid] = ln_w[tid]; s_lnb[tid] = ln_b[tid]; }
  if (tid < 2 * DH) s_woff[tid] = w_off[tid];
  __syncthreads();

  const int gid = blockIdx.x * 64 + tid;
  const int bh = gid / NN;
  const int n = gid - bh * NN;
  const int yk = n / WK, xk = n - yk * WK;

  const float* qb = q + (size_t)bh * DH * HW;
  float t[DH];
#pragma unroll
  for (int c = 0; c < DH; c++) t[c] = s_bdw[c];

  const int y0r = yk * 2 - 2, x0r = xk * 2 - 2;
  for (int dy = 0; dy < 5; dy++) {
    int y = y0r + dy;
    if (y < 0 || y >= HH) continue;
    for (int dx = 0; dx < 5; dx++) {
      int x = x0r + dx;
      if (x < 0 || x >= WW) continue;
      int off = y * WW + x;
      int widx = dy * 5 + dx;
#pragma unroll
      for (int c = 0; c < DH; c++)
        t[c] += s_wdw[c * 25 + widx] * qb[c * HW + off];
    }
  }

  float mu = 0.f;
#pragma unroll
  for (int c = 0; c < DH; c++) mu += t[c];
  mu *= (1.0f / DH);
  float var = 0.f;
#pragma unroll
  for (int c = 0; c < DH; c++) { float d = t[c] - mu; var += d * d; }
  var *= (1.0f / DH);
  float rstd = rsqrtf(var + EPSF);

  float o0 = 0.f, o1 = 0.f;
#pragma unroll
  for (int c = 0; c < DH; c++) {
    float xn = (t[c] - mu) * rstd * s_lnw[c] + s_lnb[c];
    float g = 0.5f * xn * (1.0f + erff(xn * 0.70710678118654752f));
    o0 += s_woff[c] * g;
    o1 += s_woff[DH + c] * g;
  }

  const float ref_y = (0.5f + (float)yk) / 23.0f * 2.0f - 1.0f;
  const float ref_x = (0.5f + (float)xk) / 23.0f * 2.0f - 1.0f;
  float py = fminf(fmaxf(o0 + ref_y, -1.0f), 1.0f);
  float px = fminf(fmaxf(o1 + ref_x, -1.0f), 1.0f);

  float gx = (px + 1.0f) * 0.5f * 47.0f;
  float gy = (py + 1.0f) * 0.5f * 47.0f;
  float x0f = floorf(gx), y0f = floorf(gy);
  float wx = gx - x0f, wy = gy - y0f;
  int x0 = (int)x0f, y0 = (int)y0f;
  int x0i = min(max(x0, 0), WW - 1);
  int x1i = min(max(x0 + 1, 0), WW - 1);
  int y0i = min(max(y0, 0), HH - 1);
  int y1i = min(max(y0 + 1, 0), HH - 1);
  float w00 = (1.f - wx) * (1.f - wy);
  float w01 = wx * (1.f - wy);
  float w10 = (1.f - wx) * wy;
  float w11 = wx * wy;
  int i00 = y0i * WW + x0i, i01 = y0i * WW + x1i;
  int i10 = y1i * WW + x0i, i11 = y1i * WW + x1i;

  const float* kvb = kv + (size_t)bh * DH * HW;
#pragma unroll
  for (int c = 0; c < DH; c++) {
    const float* p = kvb + (size_t)c * HW;
    float val = w00 * p[i00] + w01 * p[i01] + w10 * p[i10] + w11 * p[i11];
    kvs[((size_t)bh * DH + c) * NN + n] = val;
  }
}

// ---------------------------------------------------------------------------
// MFMA attention v4: S^T via mfma(A=K, B=Q); exp in-register; P transpose via
// wave-private swizzled LDS (2x ds_write_b64 + 1x ds_read_b128 per m-tile),
// double-buffered across iterations. 2 m-tiles per wave (32 m), 4 waves/block.
// Kb: bf16 (B,576,256); Vb: bf16 (B,256,576); O: bf16 (B,2304,256).
// Grid (2304/128 = 18, 64).
// ---------------------------------------------------------------------------
__global__ __launch_bounds__(256) void attn_mfma(const float* __restrict__ q,
                                                 const short* __restrict__ Kb,
                                                 const short* __restrict__ Vb,
                                                 short* __restrict__ O) {
  __shared__ int smem[2][4][2][256];  // [dbuf][wave][mt][16 rows x 16 dwords]
  const int tid = threadIdx.x;
  const int wave = tid >> 6;
  const int lane = tid & 63;
  const int quad = lane >> 4;
  const int l15 = lane & 15;
  const int bh = blockIdx.y;
  const int b = bh >> 3, head = bh & 7;
  const int mBase = blockIdx.x * 128 + wave * 32;

  // Q B-frags (SCALE folded): B[k=c=quad*8+j][col=m=l15], per m-tile
  short8 bq[2];
#pragma unroll
  for (int mt = 0; mt < 2; mt++) {
    const float* qp = q + ((size_t)bh * DH + quad * 8) * HW + mBase + mt * 16 + l15;
    short8 v;
#pragma unroll
    for (int j = 0; j < 8; j++) v[j] = f2bf_s(qp[(size_t)j * HW] * SCALE);
    bq[mt] = v;
  }

  const short* kbase = Kb + (size_t)b * NN * 256 + head * DH + quad * 8;
  const short* vb0 = Vb + ((size_t)b * 256 + head * DH + l15) * NN + quad * 8;
  const short* vb1 = vb0 + (size_t)16 * NN;

  f32x4 oacc[2][2] = {};
  float dsum[2] = {0.f, 0.f};

  // swizzled LDS dword offsets (chunk = 16B; physical chunk = logical ^ (row&3))
  const int row16 = l15 * 16;
  const int wr0 = row16 + (((quad >> 1) ^ (l15 & 3)) << 2) + ((quad & 1) << 1);
  const int wr1 = row16 + (((2 + (quad >> 1)) ^ (l15 & 3)) << 2) + ((quad & 1) << 1);
  const int rd = row16 + ((quad ^ (l15 & 3)) << 2);

  short8 ka0 = *(const short8*)(kbase + (size_t)l15 * 256);
  short8 ka1 = *(const short8*)(kbase + (size_t)(16 + l15) * 256);

  for (int it = 0; it < NN / 32; it++) {
    const int nb = it * 32;
    short8 va0 = *(const short8*)(vb0 + nb);
    short8 va1 = *(const short8*)(vb1 + nb);
    f32x4 z = {0.f, 0.f, 0.f, 0.f};
    f32x4 st[2][2];
    st[0][0] = __builtin_amdgcn_mfma_f32_16x16x32_bf16(ka0, bq[0], z, 0, 0, 0);
    st[0][1] = __builtin_amdgcn_mfma_f32_16x16x32_bf16(ka1, bq[0], z, 0, 0, 0);
    st[1][0] = __builtin_amdgcn_mfma_f32_16x16x32_bf16(ka0, bq[1], z, 0, 0, 0);
    st[1][1] = __builtin_amdgcn_mfma_f32_16x16x32_bf16(ka1, bq[1], z, 0, 0, 0);
    if (it + 1 < NN / 32) {  // prefetch next K frags
      ka0 = *(const short8*)(kbase + (size_t)(nb + 32 + l15) * 256);
      ka1 = *(const short8*)(kbase + (size_t)(nb + 48 + l15) * 256);
    }
    int* sm = &smem[it & 1][wave][0][0];
#pragma unroll
    for (int mt = 0; mt < 2; mt++) {
      float p0 = __expf(st[mt][0][0]), p1 = __expf(st[mt][0][1]);
      float p2 = __expf(st[mt][0][2]), p3 = __expf(st[mt][0][3]);
      float p4 = __expf(st[mt][1][0]), p5 = __expf(st[mt][1][1]);
      float p6 = __expf(st[mt][1][2]), p7 = __expf(st[mt][1][3]);
      dsum[mt] += ((p0 + p1) + (p2 + p3)) + ((p4 + p5) + (p6 + p7));
      int* base = sm + mt * 256;
      *(int2*)(base + wr0) = make_int2((int)pkrnd(p0, p1), (int)pkrnd(p2, p3));
      *(int2*)(base + wr1) = make_int2((int)pkrnd(p4, p5), (int)pkrnd(p6, p7));
    }
#pragma unroll
    for (int mt = 0; mt < 2; mt++) {
      short8 pa = *(short8*)(sm + mt * 256 + rd);
      oacc[mt][0] = __builtin_amdgcn_mfma_f32_16x16x32_bf16(pa, va0, oacc[mt][0], 0, 0, 0);
      oacc[mt][1] = __builtin_amdgcn_mfma_f32_16x16x32_bf16(pa, va1, oacc[mt][1], 0, 0, 0);
    }
  }

#pragma unroll
  for (int mt = 0; mt < 2; mt++) {
    float d = dsum[mt];
    d += __shfl_xor(d, 16);
    d += __shfl_xor(d, 32);
    short* ob = O + ((size_t)b * HW + mBase + mt * 16) * 256 + head * DH + l15;
#pragma unroll
    for (int r = 0; r < 4; r++) {
      float dr = __shfl(d, quad * 4 + r);
      float inv = 1.0f / dr;
      ob[(size_t)(quad * 4 + r) * 256] = f2bf_s(oacc[mt][0][r] * inv);
      ob[(size_t)(quad * 4 + r) * 256 + 16] = f2bf_s(oacc[mt][1][r] * inv);
    }
  }
}

// ---------------------------------------------------------------------------
// wo GEMM via MFMA with split-bf16 weights (X = attn O, bf16 m-major).
// ---------------------------------------------------------------------------
__global__ __launch_bounds__(256) void wo_gemm_mfma(const short* __restrict__ Whi,
                                                    const short* __restrict__ Wlo,
                                                    const float* __restrict__ bias,
                                                    const short* __restrict__ X,
                                                    float* __restrict__ Y) {
  const int tid = threadIdx.x;
  const int wave = tid >> 6;
  const int lane = tid & 63;
  const int quad = lane >> 4;
  const int l15 = lane & 15;
  const int b = blockIdx.z;
  const int oBase = blockIdx.y * 64 + wave * 16;
  const int mBase = blockIdx.x * 64;

  const short* wh = Whi + (size_t)(oBase + l15) * 256 + quad * 8;
  const short* wl = Wlo + (size_t)(oBase + l15) * 256 + quad * 8;
  const short* xb = X + ((size_t)b * HW + mBase) * 256 + quad * 8;

  f32x4 acc[4] = {};

  for (int k = 0; k < 256; k += 32) {
    short8 ah = *(const short8*)(wh + k);
    short8 al = *(const short8*)(wl + k);
#pragma unroll
    for (int mt = 0; mt < 4; mt++) {
      short8 bx = *(const short8*)(xb + (size_t)(mt * 16 + l15) * 256 + k);
      acc[mt] = __builtin_amdgcn_mfma_f32_16x16x32_bf16(ah, bx, acc[mt], 0, 0, 0);
      acc[mt] = __builtin_amdgcn_mfma_f32_16x16x32_bf16(al, bx, acc[mt], 0, 0, 0);
    }
  }

#pragma unroll
  for (int r = 0; r < 4; r++) {
    int o = oBase + quad * 4 + r;
    float bs = bias[o];
    float* yrow = Y + ((size_t)b * 256 + o) * HW + mBase + l15;
#pragma unroll
    for (int mt = 0; mt < 4; mt++) {
      yrow[mt * 16] = acc[mt][r] + bs;
    }
  }
}

// ---------------------------------------------------------------------------
extern "C" void kernel_launch(void* const* d_in, const int* in_sizes, int n_in,
                              void* d_out, int out_size, void* d_ws, size_t ws_size,
                              hipStream_t stream) {
  const float* x    = (const float*)d_in[0];
  const float* kv   = (const float*)d_in[1];
  const float* wq   = (const float*)d_in[2];
  const float* bq   = (const float*)d_in[3];
  const float* wk   = (const float*)d_in[4];
  const float* bk   = (const float*)d_in[5];
  const float* wv   = (const float*)d_in[6];
  const float* bv   = (const float*)d_in[7];
  const float* w_dw = (const float*)d_in[8];
  const float* b_dw = (const float*)d_in[9];
  const float* ln_w = (const float*)d_in[10];
  const float* ln_b = (const float*)d_in[11];
  const float* w_off= (const float*)d_in[12];
  const float* wo   = (const float*)d_in[13];
  const float* bo   = (const float*)d_in[14];
  float* out = (float*)d_out;
  float* ws = (float*)d_ws;

  // workspace layout (float slots) — sizes now CORRECT (bf16 count / 2):
  //   q   [0,        4718592)  : 8*256*2304 fp32
  //   R   [4718592,  7077888)  : kvs (8*256*576 fp32 = 1179648 f, dies after
  //                              v-GEMM) overlapped with O (8*2304*256 bf16
  //                              = 2359296 f, born in attn) — lifetimes disjoint
  //   Kb  [7077888,  7667712)  : 8*576*256 bf16 = 589824 f
  //   Vb  [7667712,  8257536)  : 8*256*576 bf16 = 589824 f
  //   planes [8257536, 8519680): 8 x 65536 bf16 = 262144 f
  // total 8519680 f = 34.1 MB
  float* q   = ws;
  float* kvs = ws + 4718592;
  short* O   = (short*)(ws + 4718592);
  short* Kb  = (short*)(ws + 7077888);
  short* Vb  = (short*)(ws + 7667712);
  short* Wqh = (short*)(ws + 8257536);
  short* Wql = Wqh + 65536;
  short* Wkh = Wql + 65536;
  short* Wkl = Wkh + 65536;
  short* Wvh = Wkl + 65536;
  short* Wvl = Wvh + 65536;
  short* Woh = Wvl + 65536;
  short* Wol = Woh + 65536;

  // split all four 256x256 weights into bf16 hi/lo
  split4<<<dim3(1024), dim3(256), 0, stream>>>(wq, wk, wv, wo, Wqh, Wql, Wkh, Wkl,
                                               Wvh, Wvl, Woh, Wol);
  // q = wq @ x + bq : fp32 (8,256,2304), 3-pass split MFMA
  gemm_axf_mfma<float><<<dim3(HW / 64, 8, BB), dim3(64), 0, stream>>>(
      Wqh, Wql, bq, x, q, HW);
  // offsets + bilinear sample -> kvs fp32 (8,256,576)
  dw_sample_kernel<<<dim3(BH * NN / 64), dim3(64), 0, stream>>>(
      q, kv, w_dw, b_dw, ln_w, ln_b, w_off, kvs);
  // K^T bf16 (8,576,256) and V bf16 (8,256,576)
  k_gemm_mfma<<<dim3(NN / 32, 4, BB), dim3(64), 0, stream>>>(Wkh, Wkl, bk, kvs, Kb);
  gemm_axf_mfma<__hip_bfloat16><<<dim3(NN / 64, 8, BB), dim3(64), 0, stream>>>(
      Wvh, Wvl, bv, kvs, (__hip_bfloat16*)Vb, NN);
  // MFMA attention -> O bf16 (8,2304,256); kvs is dead from here on
  attn_mfma<<<dim3(HW / 128, BH), dim3(256), 0, stream>>>(q, Kb, Vb, O);
  // out = wo @ O + bo via split-bf16 MFMA
  wo_gemm_mfma<<<dim3(HW / 64, 4, BB), dim3(256), 0, stream>>>(Woh, Wol, bo, O, out);
}